// Round 1
// baseline (638.028 us; speedup 1.0000x reference)
//
#include <hip/hip_runtime.h>
#include <math.h>

#define BATCH 8
#define CIN   512
#define DQKV  768
#define NHEAD 8
#define DH    32
#define HW    1024

#define QT 16
#define KT 16
#define LROW 36   // padded row stride (floats) for Qs/Ks/Vs, 16B-aligned
#define SROW 17   // padded row stride for Sw

// ---------------------------------------------------------------------------
// Tiled fp32 GEMM: O[b][m][n] = scale(m) * (sum_k A[m][k] * X[b][k][n] + bias[m])
// BM=128, BN=128, BK=16, 256 threads, 8x8 micro-tile per thread.
// QSCALE: rows m<256 scaled by 1/sqrt(32) (query scaling folded in).
// ---------------------------------------------------------------------------
template<int M, int K, bool QSCALE>
__global__ __launch_bounds__(256)
void conv1x1_gemm(const float* __restrict__ A, const float* __restrict__ X,
                  const float* __restrict__ bias, float* __restrict__ O)
{
    __shared__ float As[16][128];
    __shared__ float Bs[16][128];

    const int b  = blockIdx.z;
    const int m0 = blockIdx.y * 128;
    const int n0 = blockIdx.x * 128;
    const int t  = threadIdx.x;
    const int tx = t & 15;
    const int ty = t >> 4;

    const float* Xb = X + (size_t)b * K * HW;

    float acc[8][8];
    #pragma unroll
    for (int i = 0; i < 8; ++i)
        #pragma unroll
        for (int j = 0; j < 8; ++j) acc[i][j] = 0.f;

    for (int k0 = 0; k0 < K; k0 += 16) {
        // A tile: 128 m-rows x 16 k  (each 4-lane group loads one 64B row chunk)
        #pragma unroll
        for (int p = 0; p < 2; ++p) {
            int l   = t + p * 256;      // 0..511
            int row = l >> 2;           // 0..127
            int kq  = l & 3;            // float4 index within 16 k
            float4 a = *(const float4*)(A + (size_t)(m0 + row) * K + k0 + kq * 4);
            As[kq * 4 + 0][row] = a.x;
            As[kq * 4 + 1][row] = a.y;
            As[kq * 4 + 2][row] = a.z;
            As[kq * 4 + 3][row] = a.w;
        }
        // B tile: 16 k-rows x 128 n
        #pragma unroll
        for (int p = 0; p < 2; ++p) {
            int l  = t + p * 256;
            int kk = l >> 5;            // 0..15
            int jq = l & 31;            // *4 floats
            *(float4*)(&Bs[kk][jq * 4]) =
                *(const float4*)(Xb + (size_t)(k0 + kk) * HW + n0 + jq * 4);
        }
        __syncthreads();

        #pragma unroll
        for (int kk = 0; kk < 16; ++kk) {
            float ar[8], br[8];
            #pragma unroll
            for (int i = 0; i < 8; ++i) ar[i] = As[kk][ty + 16 * i];
            #pragma unroll
            for (int j = 0; j < 8; ++j) br[j] = Bs[kk][tx + 16 * j];
            #pragma unroll
            for (int i = 0; i < 8; ++i)
                #pragma unroll
                for (int j = 0; j < 8; ++j)
                    acc[i][j] += ar[i] * br[j];
        }
        __syncthreads();
    }

    #pragma unroll
    for (int i = 0; i < 8; ++i) {
        int m = m0 + ty + 16 * i;
        float bi = bias[m];
        float sc = 1.0f;
        if (QSCALE) sc = (m < 256) ? 0.17677669529663687f : 1.0f;  // 1/sqrt(32)
        #pragma unroll
        for (int j = 0; j < 8; ++j) {
            int n = n0 + tx + 16 * j;
            O[((size_t)b * M + m) * HW + n] = (acc[i][j] + bi) * sc;
        }
    }
}

// ---------------------------------------------------------------------------
// Attention core. One workgroup = (b, 16-q tile). Streams k in tiles of 16.
// Softmax is across the 8 heads (axis=1 of (b,n,q,k)) -> pointwise in (q,k).
// qkv layout: [b][768][1024] with q rows 0..255 (scale pre-folded),
// k rows 256..511, v rows 512..767; head n owns rows n*32..n*32+31.
// Output written directly in the reference's reshaped image layout:
//   attn[b][n*32 + (q>>5)][(q&31)*32 + d]
// ---------------------------------------------------------------------------
__global__ __launch_bounds__(256)
void attn_kernel(const float* __restrict__ qkv, float* __restrict__ attn)
{
    __shared__ float Qs[NHEAD * QT * LROW];   // [n][qq][d], 4608 f
    __shared__ float Ks[NHEAD * KT * LROW];   // [n][kk][d], 4608 f
    __shared__ float Vs[NHEAD * KT * LROW];   // [n][kk][d], 4608 f
    __shared__ float Sw[NHEAD * QT * SROW];   // [n][qq][kk], 2176 f  (total 64000 B)

    const int t  = threadIdx.x;
    const int b  = blockIdx.y;
    const int q0 = blockIdx.x * QT;

    const float* qk = qkv + (size_t)b * DQKV * HW;

    // ---- load Q tile: rows (n,d) = 256, 16 q's each ----
    #pragma unroll
    for (int p = 0; p < 4; ++p) {
        int l   = t + p * 256;            // 0..1023
        int row = l >> 2;                 // 0..255  (n = row>>5, d = row&31)
        int c4  = l & 3;
        float4 v = *(const float4*)(qk + (size_t)row * HW + q0 + c4 * 4);
        int n = row >> 5, d = row & 31;
        float* dst = &Qs[(n * QT) * LROW + d];
        dst[(c4 * 4 + 0) * LROW] = v.x;
        dst[(c4 * 4 + 1) * LROW] = v.y;
        dst[(c4 * 4 + 2) * LROW] = v.z;
        dst[(c4 * 4 + 3) * LROW] = v.w;
    }

    // logits mapping: thread -> (n_l, q-pair qp, k-group kg)
    const int n_l = t >> 5;          // 0..7
    const int r   = t & 31;
    const int qp  = r >> 2;          // 0..7  -> q = qp*2 + i
    const int kg  = r & 3;           // 0..3  -> k = kg*4 + j
    // PV mapping: thread -> (n_l, q_p, d-half dh)
    const int q_p = r >> 1;          // 0..15
    const int dh  = (r & 1) * 16;    // 0 or 16

    float4 acc[4];
    #pragma unroll
    for (int j = 0; j < 4; ++j) acc[j] = make_float4(0.f, 0.f, 0.f, 0.f);

    for (int k0 = 0; k0 < HW; k0 += KT) {
        __syncthreads();   // previous iteration done with Ks/Vs/Sw (and Qs stored, 1st iter)

        // ---- load K & V tiles ----
        #pragma unroll
        for (int p = 0; p < 4; ++p) {
            int l   = t + p * 256;
            int row = l >> 2;             // 0..255
            int c4  = l & 3;
            int n = row >> 5, d = row & 31;
            float4 kv = *(const float4*)(qk + (size_t)(256 + row) * HW + k0 + c4 * 4);
            float4 vv = *(const float4*)(qk + (size_t)(512 + row) * HW + k0 + c4 * 4);
            float* dK = &Ks[(n * KT) * LROW + d];
            float* dV = &Vs[(n * KT) * LROW + d];
            dK[(c4 * 4 + 0) * LROW] = kv.x;  dV[(c4 * 4 + 0) * LROW] = vv.x;
            dK[(c4 * 4 + 1) * LROW] = kv.y;  dV[(c4 * 4 + 1) * LROW] = vv.y;
            dK[(c4 * 4 + 2) * LROW] = kv.z;  dV[(c4 * 4 + 2) * LROW] = vv.z;
            dK[(c4 * 4 + 3) * LROW] = kv.w;  dV[(c4 * 4 + 3) * LROW] = vv.w;
        }
        __syncthreads();

        // ---- logits: S[n][q][k] = sum_d Q[n][q][d]*K[n][k][d]  (2q x 4k per thread) ----
        {
            float s[2][4];
            #pragma unroll
            for (int i = 0; i < 2; ++i)
                #pragma unroll
                for (int j = 0; j < 4; ++j) s[i][j] = 0.f;
            #pragma unroll
            for (int dc = 0; dc < DH; dc += 4) {
                float4 qv0 = *(const float4*)&Qs[(n_l * QT + qp * 2 + 0) * LROW + dc];
                float4 qv1 = *(const float4*)&Qs[(n_l * QT + qp * 2 + 1) * LROW + dc];
                #pragma unroll
                for (int j = 0; j < 4; ++j) {
                    float4 kv = *(const float4*)&Ks[(n_l * KT + kg * 4 + j) * LROW + dc];
                    s[0][j] += qv0.x * kv.x + qv0.y * kv.y + qv0.z * kv.z + qv0.w * kv.w;
                    s[1][j] += qv1.x * kv.x + qv1.y * kv.y + qv1.z * kv.z + qv1.w * kv.w;
                }
            }
            #pragma unroll
            for (int i = 0; i < 2; ++i)
                #pragma unroll
                for (int j = 0; j < 4; ++j)
                    Sw[(n_l * QT + qp * 2 + i) * SROW + kg * 4 + j] = s[i][j];
        }
        __syncthreads();

        // ---- softmax across heads: one (q,k) pair per thread ----
        {
            int q = t >> 4, k = t & 15;
            float* sp = &Sw[q * SROW + k];
            float vals[NHEAD];
            float m = -1e30f;
            #pragma unroll
            for (int n = 0; n < NHEAD; ++n) {
                vals[n] = sp[n * QT * SROW];
                m = fmaxf(m, vals[n]);
            }
            float ssum = 0.f;
            #pragma unroll
            for (int n = 0; n < NHEAD; ++n) {
                vals[n] = __expf(vals[n] - m);
                ssum += vals[n];
            }
            float inv = 1.0f / ssum;
            #pragma unroll
            for (int n = 0; n < NHEAD; ++n)
                sp[n * QT * SROW] = vals[n] * inv;
        }
        __syncthreads();

        // ---- PV: acc[n_l][q_p][dh..dh+15] += sum_k w * V ----
        #pragma unroll
        for (int kk = 0; kk < KT; ++kk) {
            float w = Sw[(n_l * QT + q_p) * SROW + kk];
            const float4* vr = (const float4*)&Vs[(n_l * KT + kk) * LROW + dh];
            #pragma unroll
            for (int j = 0; j < 4; ++j) {
                float4 vv = vr[j];
                acc[j].x += w * vv.x;
                acc[j].y += w * vv.y;
                acc[j].z += w * vv.z;
                acc[j].w += w * vv.w;
            }
        }
    }

    // ---- write attn image: value(b, n_l, qg=q0+q_p, d=dh+0..15) ----
    // channel = n_l*32 + (qg>>5),  hw = (qg&31)*32 + d
    {
        int qg = q0 + q_p;
        size_t base = (((size_t)b * 256 + n_l * 32 + (qg >> 5)) * HW) + (qg & 31) * 32 + dh;
        #pragma unroll
        for (int j = 0; j < 4; ++j)
            *(float4*)(attn + base + j * 4) = acc[j];
    }
}

// ---------------------------------------------------------------------------
extern "C" void kernel_launch(void* const* d_in, const int* in_sizes, int n_in,
                              void* d_out, int out_size, void* d_ws, size_t ws_size,
                              hipStream_t stream)
{
    const float* x      = (const float*)d_in[0];
    const float* w_qkv  = (const float*)d_in[1];
    const float* b_qkv  = (const float*)d_in[2];
    const float* w_attn = (const float*)d_in[3];
    const float* b_attn = (const float*)d_in[4];
    float* out = (float*)d_out;

    float* qkv_ws  = (float*)d_ws;                          // 8*768*1024 f = 25.2 MB
    float* attn_ws = qkv_ws + (size_t)BATCH * DQKV * HW;    // 8*256*1024 f =  8.4 MB

    // 1) QKV projection (query scale folded into rows m<256)
    conv1x1_gemm<DQKV, CIN, true>
        <<<dim3(HW / 128, DQKV / 128, BATCH), 256, 0, stream>>>(w_qkv, x, b_qkv, qkv_ws);

    // 2) fused attention core (head-axis softmax), writes reshaped image layout
    attn_kernel<<<dim3(HW / QT, BATCH), 256, 0, stream>>>(qkv_ws, attn_ws);

    // 3) output projection
    conv1x1_gemm<512, 256, false>
        <<<dim3(HW / 128, 512 / 128, BATCH), 256, 0, stream>>>(w_attn, attn_ws, b_attn, out);
}

// Round 2
// 406.727 us; speedup vs baseline: 1.5687x; 1.5687x over previous
//
#include <hip/hip_runtime.h>
#include <math.h>

#define BATCH 8
#define CIN   512
#define DQKV  768
#define NHEAD 8
#define DH    32
#define HW    1024

typedef __attribute__((ext_vector_type(8))) short  short8;
typedef __attribute__((ext_vector_type(4))) float  float4v;

__device__ inline ushort f2bf(float f) {
    union { float f; unsigned u; } c; c.f = f;
    unsigned u = c.u + 0x7fffu + ((c.u >> 16) & 1u);   // RNE
    return (ushort)(u >> 16);
}

// ---------------------------------------------------------------------------
// Tiled fp32 GEMM: O[b][m][n] = scale(m) * (sum_k A[m][k] * X[b][k][n] + bias[m])
// (unchanged from round 0)
// ---------------------------------------------------------------------------
template<int M, int K, bool QSCALE>
__global__ __launch_bounds__(256)
void conv1x1_gemm(const float* __restrict__ A, const float* __restrict__ X,
                  const float* __restrict__ bias, float* __restrict__ O)
{
    __shared__ float As[16][128];
    __shared__ float Bs[16][128];

    const int b  = blockIdx.z;
    const int m0 = blockIdx.y * 128;
    const int n0 = blockIdx.x * 128;
    const int t  = threadIdx.x;
    const int tx = t & 15;
    const int ty = t >> 4;

    const float* Xb = X + (size_t)b * K * HW;

    float acc[8][8];
    #pragma unroll
    for (int i = 0; i < 8; ++i)
        #pragma unroll
        for (int j = 0; j < 8; ++j) acc[i][j] = 0.f;

    for (int k0 = 0; k0 < K; k0 += 16) {
        #pragma unroll
        for (int p = 0; p < 2; ++p) {
            int l   = t + p * 256;
            int row = l >> 2;
            int kq  = l & 3;
            float4 a = *(const float4*)(A + (size_t)(m0 + row) * K + k0 + kq * 4);
            As[kq * 4 + 0][row] = a.x;
            As[kq * 4 + 1][row] = a.y;
            As[kq * 4 + 2][row] = a.z;
            As[kq * 4 + 3][row] = a.w;
        }
        #pragma unroll
        for (int p = 0; p < 2; ++p) {
            int l  = t + p * 256;
            int kk = l >> 5;
            int jq = l & 31;
            *(float4*)(&Bs[kk][jq * 4]) =
                *(const float4*)(Xb + (size_t)(k0 + kk) * HW + n0 + jq * 4);
        }
        __syncthreads();

        #pragma unroll
        for (int kk = 0; kk < 16; ++kk) {
            float ar[8], br[8];
            #pragma unroll
            for (int i = 0; i < 8; ++i) ar[i] = As[kk][ty + 16 * i];
            #pragma unroll
            for (int j = 0; j < 8; ++j) br[j] = Bs[kk][tx + 16 * j];
            #pragma unroll
            for (int i = 0; i < 8; ++i)
                #pragma unroll
                for (int j = 0; j < 8; ++j)
                    acc[i][j] += ar[i] * br[j];
        }
        __syncthreads();
    }

    #pragma unroll
    for (int i = 0; i < 8; ++i) {
        int m = m0 + ty + 16 * i;
        float bi = bias[m];
        float sc = 1.0f;
        if (QSCALE) sc = (m < 256) ? 0.17677669529663687f : 1.0f;
        #pragma unroll
        for (int j = 0; j < 8; ++j) {
            int n = n0 + tx + 16 * j;
            O[((size_t)b * M + m) * HW + n] = (acc[i][j] + bi) * sc;
        }
    }
}

// ---------------------------------------------------------------------------
// MFMA attention core. One block = (b, 16-q tile); streams k in tiles of 32.
// 4 waves, wave w owns heads 2w,2w+1. Softmax across the 8 heads (pointwise
// per (q,k)) via fp32 LDS round-trip. bf16 fragments, fp32 accumulation.
//
// LDS layouts (ushort stride 40 -> rows 16B-aligned for ds_read_b128, 2-way
// bank aliasing = free):
//   Qs[n][q (16)][d (32)]  A-frag source for logits
//   Ks[n][k (32)][d (32)]  B-frag source for logits (transposed on staging)
//   Vs[n][d (32)][k (32)]  B-frag source for PV (natural layout copy)
//   Ws[n][q (16)][k (32)]  A-frag source for PV (bf16 softmax weights)
//   Ss fp32, head stride 529 dwords (529%32=17 -> 8-head reads conflict-free)
// ---------------------------------------------------------------------------
__global__ __launch_bounds__(256, 2)
void attn_kernel(const float* __restrict__ qkv, float* __restrict__ attn)
{
    __shared__ __align__(16) ushort Qs[NHEAD * 16 * 40];
    __shared__ __align__(16) ushort Ks[NHEAD * 32 * 40];
    __shared__ __align__(16) ushort Vs[NHEAD * 32 * 40];
    __shared__ __align__(16) ushort Ws[NHEAD * 16 * 40];
    __shared__ float  Ss[NHEAD * 529];          // [n][q*33 + k]

    const int t    = threadIdx.x;
    const int b    = blockIdx.y;
    const int q0   = blockIdx.x * 16;
    const int wave = t >> 6;
    const int lane = t & 63;
    const int l16  = lane & 15;
    const int quad = lane >> 4;

    const float* qk = qkv + (size_t)b * DQKV * HW;

    // ---- stage Q tile (once): global rows n*32+d, cols q0..q0+15 -> Qs[n][q][d]
    #pragma unroll
    for (int p = 0; p < 4; ++p) {
        int l   = t + p * 256;            // 0..1023
        int row = l >> 2;                 // channel 0..255
        int c4  = l & 3;                  // q-chunk
        float4 v = *(const float4*)(qk + (size_t)row * HW + q0 + c4 * 4);
        int n = row >> 5, d = row & 31;
        ushort* dst = &Qs[(n * 16 + c4 * 4) * 40 + d];
        dst[0 * 40] = f2bf(v.x);
        dst[1 * 40] = f2bf(v.y);
        dst[2 * 40] = f2bf(v.z);
        dst[3 * 40] = f2bf(v.w);
    }

    float4v acc[2][2];                    // [head-in-wave][d-half]
    #pragma unroll
    for (int i = 0; i < 2; ++i)
        #pragma unroll
        for (int j = 0; j < 2; ++j)
            acc[i][j] = (float4v){0.f, 0.f, 0.f, 0.f};

    const int sq = t >> 4;                // softmax q (0..15)
    const int sk = (t & 15) * 2;          // softmax k pair base

    for (int k0 = 0; k0 < HW; k0 += 32) {
        __syncthreads();                  // prev iter done with Ks/Vs/Ws

        // ---- stage K (transposed) and V (natural) tiles, fp32 -> bf16 ----
        #pragma unroll
        for (int p = 0; p < 8; ++p) {
            int l   = t + p * 256;        // 0..2047
            int row = l >> 3;             // channel 0..255
            int c4  = l & 7;              // k-chunk
            int n = row >> 5, d = row & 31;
            float4 kv = *(const float4*)(qk + (size_t)(256 + row) * HW + k0 + c4 * 4);
            ushort* dK = &Ks[(n * 32 + c4 * 4) * 40 + d];
            dK[0 * 40] = f2bf(kv.x);
            dK[1 * 40] = f2bf(kv.y);
            dK[2 * 40] = f2bf(kv.z);
            dK[3 * 40] = f2bf(kv.w);
            float4 vv = *(const float4*)(qk + (size_t)(512 + row) * HW + k0 + c4 * 4);
            uint2 pk;
            pk.x = (uint)f2bf(vv.x) | ((uint)f2bf(vv.y) << 16);
            pk.y = (uint)f2bf(vv.z) | ((uint)f2bf(vv.w) << 16);
            *(uint2*)&Vs[(n * 32 + d) * 40 + c4 * 4] = pk;
        }
        __syncthreads();

        // ---- logits: S[n][q][k] = sum_d Q[q][d] K[k][d], one MFMA per 16x16
        #pragma unroll
        for (int hh = 0; hh < 2; ++hh) {
            int h = wave * 2 + hh;
            short8 a = *(const short8*)&Qs[(h * 16 + l16) * 40 + quad * 8];
            #pragma unroll
            for (int ko = 0; ko < 2; ++ko) {
                short8 bfr = *(const short8*)&Ks[(h * 32 + ko * 16 + l16) * 40 + quad * 8];
                float4v s = __builtin_amdgcn_mfma_f32_16x16x32_bf16(
                    a, bfr, (float4v){0.f, 0.f, 0.f, 0.f}, 0, 0, 0);
                float* sp = &Ss[h * 529 + (quad * 4) * 33 + ko * 16 + l16];
                #pragma unroll
                for (int r = 0; r < 4; ++r) sp[r * 33] = s[r];
            }
        }
        __syncthreads();

        // ---- softmax across heads; write bf16 weights. One (q, k-pair)/thread
        {
            float v[NHEAD][2];
            float m0v = -1e30f, m1v = -1e30f;
            #pragma unroll
            for (int n = 0; n < NHEAD; ++n) {
                v[n][0] = Ss[n * 529 + sq * 33 + sk + 0];
                v[n][1] = Ss[n * 529 + sq * 33 + sk + 1];
                m0v = fmaxf(m0v, v[n][0]);
                m1v = fmaxf(m1v, v[n][1]);
            }
            float s0 = 0.f, s1 = 0.f;
            #pragma unroll
            for (int n = 0; n < NHEAD; ++n) {
                v[n][0] = __expf(v[n][0] - m0v);
                v[n][1] = __expf(v[n][1] - m1v);
                s0 += v[n][0];
                s1 += v[n][1];
            }
            float i0 = 1.0f / s0, i1 = 1.0f / s1;
            #pragma unroll
            for (int n = 0; n < NHEAD; ++n) {
                uint pk = (uint)f2bf(v[n][0] * i0) | ((uint)f2bf(v[n][1] * i1) << 16);
                *(uint*)&Ws[(n * 16 + sq) * 40 + sk] = pk;
            }
        }
        __syncthreads();

        // ---- PV: O[n][q][d] += sum_k W[q][k] V[k][d], one MFMA per 16x16
        #pragma unroll
        for (int hh = 0; hh < 2; ++hh) {
            int h = wave * 2 + hh;
            short8 a = *(const short8*)&Ws[(h * 16 + l16) * 40 + quad * 8];
            #pragma unroll
            for (int dd = 0; dd < 2; ++dd) {
                short8 bfr = *(const short8*)&Vs[(h * 32 + dd * 16 + l16) * 40 + quad * 8];
                acc[hh][dd] = __builtin_amdgcn_mfma_f32_16x16x32_bf16(
                    a, bfr, acc[hh][dd], 0, 0, 0);
            }
        }
    }

    // ---- epilogue: write reference's reshaped image layout ----
    // channel = h*32 + (qg>>5), hw = (qg&31)*32 + d
    #pragma unroll
    for (int hh = 0; hh < 2; ++hh) {
        int h = wave * 2 + hh;
        #pragma unroll
        for (int dd = 0; dd < 2; ++dd) {
            #pragma unroll
            for (int r = 0; r < 4; ++r) {
                int qg = q0 + quad * 4 + r;
                size_t addr = ((size_t)b * 256 + h * 32 + (qg >> 5)) * HW
                            + (size_t)(qg & 31) * 32 + dd * 16 + l16;
                attn[addr] = acc[hh][dd][r];
            }
        }
    }
}

// ---------------------------------------------------------------------------
extern "C" void kernel_launch(void* const* d_in, const int* in_sizes, int n_in,
                              void* d_out, int out_size, void* d_ws, size_t ws_size,
                              hipStream_t stream)
{
    const float* x      = (const float*)d_in[0];
    const float* w_qkv  = (const float*)d_in[1];
    const float* b_qkv  = (const float*)d_in[2];
    const float* w_attn = (const float*)d_in[3];
    const float* b_attn = (const float*)d_in[4];
    float* out = (float*)d_out;

    float* qkv_ws  = (float*)d_ws;                          // 8*768*1024 f = 25.2 MB
    float* attn_ws = qkv_ws + (size_t)BATCH * DQKV * HW;    // 8*256*1024 f =  8.4 MB

    // 1) QKV projection (query scale folded into rows m<256)
    conv1x1_gemm<DQKV, CIN, true>
        <<<dim3(HW / 128, DQKV / 128, BATCH), 256, 0, stream>>>(w_qkv, x, b_qkv, qkv_ws);

    // 2) MFMA attention core (head-axis softmax), writes reshaped image layout
    attn_kernel<<<dim3(HW / 16, BATCH), 256, 0, stream>>>(qkv_ws, attn_ws);

    // 3) output projection
    conv1x1_gemm<512, 256, false>
        <<<dim3(HW / 128, 512 / 128, BATCH), 256, 0, stream>>>(w_attn, attn_ws, b_attn, out);
}

// Round 3
// 185.055 us; speedup vs baseline: 3.4478x; 2.1979x over previous
//
#include <hip/hip_runtime.h>
#include <math.h>

#define BATCH 8
#define CIN   512
#define DQKV  768
#define NHEAD 8
#define HW    1024

typedef __attribute__((ext_vector_type(8))) short  short8;
typedef __attribute__((ext_vector_type(4))) float  float4v;

__device__ __forceinline__ ushort f2bf(float f) {
    union { float f; unsigned u; } c; c.f = f;
    unsigned u = c.u + 0x7fffu + ((c.u >> 16) & 1u);   // RNE
    return (ushort)(u >> 16);
}

__device__ __forceinline__ void async_ld16(const ushort* g, ushort* l) {
    auto gp = (const __attribute__((address_space(1))) unsigned int*)g;
    auto lp = (__attribute__((address_space(3))) unsigned int*)l;
    __builtin_amdgcn_global_load_lds(gp, lp, 16, 0, 0);
}

// ---------------------------------------------------------------------------
// Transpose + fp32->bf16: per batch, in [K][N] fp32 -> out [N][K] bf16.
// 64x64 tiles, coalesced on both sides via LDS (65-stride pad).
// ---------------------------------------------------------------------------
__global__ __launch_bounds__(256)
void transpose_cvt(const float* __restrict__ in, ushort* __restrict__ out,
                   int K, int N)
{
    __shared__ float Ts[64][65];
    const int b  = blockIdx.z;
    const int k0 = blockIdx.y * 64;
    const int n0 = blockIdx.x * 64;
    const int t  = threadIdx.x;
    const float* ib = in + (size_t)b * K * N;
    ushort*      ob = out + (size_t)b * N * K;

    const int r  = t >> 4;
    const int c4 = (t & 15) * 4;
    #pragma unroll
    for (int p = 0; p < 4; ++p) {
        float4 v = *(const float4*)(ib + (size_t)(k0 + r + 16 * p) * N + n0 + c4);
        Ts[r + 16 * p][c4 + 0] = v.x;
        Ts[r + 16 * p][c4 + 1] = v.y;
        Ts[r + 16 * p][c4 + 2] = v.z;
        Ts[r + 16 * p][c4 + 3] = v.w;
    }
    __syncthreads();

    const int nl = t >> 3;
    const int kc = (t & 7) * 8;
    #pragma unroll
    for (int p = 0; p < 2; ++p) {
        int n = nl + 32 * p;
        uint4 u;
        u.x = (uint)f2bf(Ts[kc + 0][n]) | ((uint)f2bf(Ts[kc + 1][n]) << 16);
        u.y = (uint)f2bf(Ts[kc + 2][n]) | ((uint)f2bf(Ts[kc + 3][n]) << 16);
        u.z = (uint)f2bf(Ts[kc + 4][n]) | ((uint)f2bf(Ts[kc + 5][n]) << 16);
        u.w = (uint)f2bf(Ts[kc + 6][n]) | ((uint)f2bf(Ts[kc + 7][n]) << 16);
        *(uint4*)(ob + (size_t)(n0 + n) * K + k0 + kc) = u;
    }
}

// elementwise fp32 -> bf16 (weights), 8 elems/thread
__global__ void cvt_bf16(const float* __restrict__ in, ushort* __restrict__ out, int n8)
{
    int i = blockIdx.x * blockDim.x + threadIdx.x;
    if (i >= n8) return;
    const float4* p = (const float4*)(in + (size_t)i * 8);
    float4 a = p[0], b = p[1];
    uint4 u;
    u.x = (uint)f2bf(a.x) | ((uint)f2bf(a.y) << 16);
    u.y = (uint)f2bf(a.z) | ((uint)f2bf(a.w) << 16);
    u.z = (uint)f2bf(b.x) | ((uint)f2bf(b.y) << 16);
    u.w = (uint)f2bf(b.z) | ((uint)f2bf(b.w) << 16);
    *(uint4*)(out + (size_t)i * 8) = u;
}

// ---------------------------------------------------------------------------
// bf16 MFMA GEMM (m97 structure): O[b][m][n] = sum_k A[m][k] * Bt[b][n][k]
// + bias[m], optional q-scale on rows m<256; output bf16 or fp32.
// 128x128 tile, BK=64, 4 waves each 64x64 (4x4 of 16x16x32 MFMA).
// global_load_lds width-16 staging; XOR chunk swizzle applied on the GLOBAL
// address side (lane->LDS stays lane-linear) -> conflict-free ds_read_b128.
// ---------------------------------------------------------------------------
template<int M, int K, bool QSCALE, bool OUTBF>
__global__ __launch_bounds__(256, 2)
void gemm_bt(const ushort* __restrict__ A, const ushort* __restrict__ Bt,
             const float* __restrict__ bias, void* __restrict__ Oo)
{
    __shared__ __align__(16) ushort As[128 * 64];
    __shared__ __align__(16) ushort Bs[128 * 64];

    const int b    = blockIdx.z;
    const int m0   = blockIdx.y * 128;
    const int n0   = blockIdx.x * 128;
    const int t    = threadIdx.x;
    const int lane = t & 63;
    const int wave = t >> 6;
    const int l16  = lane & 15;
    const int quad = lane >> 4;
    const int wm   = (wave & 1) * 64;
    const int wn   = (wave >> 1) * 64;

    const ushort* Bb = Bt + (size_t)b * HW * K;

    float4v acc[4][4];
    #pragma unroll
    for (int i = 0; i < 4; ++i)
        #pragma unroll
        for (int j = 0; j < 4; ++j)
            acc[i][j] = (float4v){0.f, 0.f, 0.f, 0.f};

    const int srow = t >> 3;       // staging row base (0..31)
    const int sg   = t & 7;        // 16B chunk within 64-short row

    for (int k0 = 0; k0 < K; k0 += 64) {
        __syncthreads();
        #pragma unroll
        for (int is = 0; is < 4; ++is) {
            int row = srow + is * 32;
            int gch = sg ^ (row & 7);                       // inverse swizzle on global side
            async_ld16(A  + (size_t)(m0 + row) * K + k0 + gch * 8,
                       As + (size_t)t * 8 + is * 2048);
            async_ld16(Bb + (size_t)(n0 + row) * K + k0 + gch * 8,
                       Bs + (size_t)t * 8 + is * 2048);
        }
        __syncthreads();

        #pragma unroll
        for (int ks = 0; ks < 2; ++ks) {
            short8 af[4], bf[4];
            #pragma unroll
            for (int i = 0; i < 4; ++i) {
                int row = wm + i * 16 + l16;
                int ch  = (ks * 4 + quad) ^ (row & 7);
                af[i] = *(const short8*)&As[row * 64 + ch * 8];
            }
            #pragma unroll
            for (int j = 0; j < 4; ++j) {
                int row = wn + j * 16 + l16;
                int ch  = (ks * 4 + quad) ^ (row & 7);
                bf[j] = *(const short8*)&Bs[row * 64 + ch * 8];
            }
            #pragma unroll
            for (int i = 0; i < 4; ++i)
                #pragma unroll
                for (int j = 0; j < 4; ++j)
                    acc[i][j] = __builtin_amdgcn_mfma_f32_16x16x32_bf16(
                        af[i], bf[j], acc[i][j], 0, 0, 0);
        }
    }

    #pragma unroll
    for (int i = 0; i < 4; ++i) {
        #pragma unroll
        for (int rr = 0; rr < 4; ++rr) {
            int m = m0 + wm + i * 16 + quad * 4 + rr;
            float bi = bias[m];
            float sc = QSCALE ? ((m < 256) ? 0.17677669529663687f : 1.0f) : 1.0f;
            #pragma unroll
            for (int j = 0; j < 4; ++j) {
                int n = n0 + wn + j * 16 + l16;
                float val = (acc[i][j][rr] + bi) * sc;
                if (OUTBF)
                    ((ushort*)Oo)[((size_t)b * M + m) * HW + n] = f2bf(val);
                else
                    ((float*)Oo)[((size_t)b * M + m) * HW + n] = val;
            }
        }
    }
}

// ---------------------------------------------------------------------------
// MFMA attention core (bf16 qkv input). One block = (b, 16-q tile); k tiles
// of 32. 4 waves, wave w owns heads 2w,2w+1. Head-axis softmax via fp32 LDS.
// ---------------------------------------------------------------------------
__global__ __launch_bounds__(256, 2)
void attn_kernel(const ushort* __restrict__ qkv, float* __restrict__ attn)
{
    __shared__ __align__(16) ushort Qs[NHEAD * 16 * 40];
    __shared__ __align__(16) ushort Ks[NHEAD * 32 * 40];
    __shared__ __align__(16) ushort Vs[NHEAD * 32 * 40];
    __shared__ __align__(16) ushort Ws[NHEAD * 16 * 40];
    __shared__ float  Ss[NHEAD * 529];          // [n][q*33 + k]

    const int t    = threadIdx.x;
    const int b    = blockIdx.y;
    const int q0   = blockIdx.x * 16;
    const int wave = t >> 6;
    const int lane = t & 63;
    const int l16  = lane & 15;
    const int quad = lane >> 4;

    const ushort* qk = qkv + (size_t)b * DQKV * HW;

    // ---- stage Q tile (transposed): Qs[n][q][d] ----
    #pragma unroll
    for (int p = 0; p < 2; ++p) {
        int tt  = t + p * 256;            // 0..511
        int row = tt >> 1;                // channel 0..255
        int c8  = (tt & 1) * 8;           // q-chunk
        uint4 u = *(const uint4*)(qk + (size_t)row * HW + q0 + c8);
        ushort v[8]; *(uint4*)v = u;
        int n = row >> 5, d = row & 31;
        ushort* dst = &Qs[(n * 16 + c8) * 40 + d];
        #pragma unroll
        for (int j = 0; j < 8; ++j) dst[j * 40] = v[j];
    }

    float4v acc[2][2];
    #pragma unroll
    for (int i = 0; i < 2; ++i)
        #pragma unroll
        for (int j = 0; j < 2; ++j)
            acc[i][j] = (float4v){0.f, 0.f, 0.f, 0.f};

    const int sq = t >> 4;
    const int sk = (t & 15) * 2;

    for (int k0 = 0; k0 < HW; k0 += 32) {
        __syncthreads();

        // ---- stage K (transposed) and V (natural) ----
        #pragma unroll
        for (int p = 0; p < 4; ++p) {
            int tt  = t + p * 256;        // 0..1023
            int row = tt >> 2;            // channel 0..255
            int c8  = (tt & 3) * 8;       // k-chunk
            int n = row >> 5, d = row & 31;
            uint4 ku = *(const uint4*)(qk + (size_t)(256 + row) * HW + k0 + c8);
            ushort kv[8]; *(uint4*)kv = ku;
            ushort* dK = &Ks[(n * 32 + c8) * 40 + d];
            #pragma unroll
            for (int j = 0; j < 8; ++j) dK[j * 40] = kv[j];
            uint4 vu = *(const uint4*)(qk + (size_t)(512 + row) * HW + k0 + c8);
            *(uint4*)&Vs[(n * 32 + d) * 40 + c8] = vu;
        }
        __syncthreads();

        // ---- logits ----
        #pragma unroll
        for (int hh = 0; hh < 2; ++hh) {
            int h = wave * 2 + hh;
            short8 a = *(const short8*)&Qs[(h * 16 + l16) * 40 + quad * 8];
            #pragma unroll
            for (int ko = 0; ko < 2; ++ko) {
                short8 bfr = *(const short8*)&Ks[(h * 32 + ko * 16 + l16) * 40 + quad * 8];
                float4v s = __builtin_amdgcn_mfma_f32_16x16x32_bf16(
                    a, bfr, (float4v){0.f, 0.f, 0.f, 0.f}, 0, 0, 0);
                float* sp = &Ss[h * 529 + (quad * 4) * 33 + ko * 16 + l16];
                #pragma unroll
                for (int r = 0; r < 4; ++r) sp[r * 33] = s[r];
            }
        }
        __syncthreads();

        // ---- head-axis softmax -> bf16 weights ----
        {
            float v[NHEAD][2];
            float m0v = -1e30f, m1v = -1e30f;
            #pragma unroll
            for (int n = 0; n < NHEAD; ++n) {
                v[n][0] = Ss[n * 529 + sq * 33 + sk + 0];
                v[n][1] = Ss[n * 529 + sq * 33 + sk + 1];
                m0v = fmaxf(m0v, v[n][0]);
                m1v = fmaxf(m1v, v[n][1]);
            }
            float s0 = 0.f, s1 = 0.f;
            #pragma unroll
            for (int n = 0; n < NHEAD; ++n) {
                v[n][0] = __expf(v[n][0] - m0v);
                v[n][1] = __expf(v[n][1] - m1v);
                s0 += v[n][0];
                s1 += v[n][1];
            }
            float i0 = 1.0f / s0, i1 = 1.0f / s1;
            #pragma unroll
            for (int n = 0; n < NHEAD; ++n) {
                uint pk = (uint)f2bf(v[n][0] * i0) | ((uint)f2bf(v[n][1] * i1) << 16);
                *(uint*)&Ws[(n * 16 + sq) * 40 + sk] = pk;
            }
        }
        __syncthreads();

        // ---- PV ----
        #pragma unroll
        for (int hh = 0; hh < 2; ++hh) {
            int h = wave * 2 + hh;
            short8 a = *(const short8*)&Ws[(h * 16 + l16) * 40 + quad * 8];
            #pragma unroll
            for (int dd = 0; dd < 2; ++dd) {
                short8 bfr = *(const short8*)&Vs[(h * 32 + dd * 16 + l16) * 40 + quad * 8];
                acc[hh][dd] = __builtin_amdgcn_mfma_f32_16x16x32_bf16(
                    a, bfr, acc[hh][dd], 0, 0, 0);
            }
        }
    }

    // ---- epilogue: reference's reshaped image layout, fp32 ----
    #pragma unroll
    for (int hh = 0; hh < 2; ++hh) {
        int h = wave * 2 + hh;
        #pragma unroll
        for (int dd = 0; dd < 2; ++dd) {
            #pragma unroll
            for (int r = 0; r < 4; ++r) {
                int qg = q0 + quad * 4 + r;
                size_t addr = ((size_t)b * 256 + h * 32 + (qg >> 5)) * HW
                            + (size_t)(qg & 31) * 32 + dd * 16 + l16;
                attn[addr] = acc[hh][dd][r];
            }
        }
    }
}

// ---------------------------------------------------------------------------
extern "C" void kernel_launch(void* const* d_in, const int* in_sizes, int n_in,
                              void* d_out, int out_size, void* d_ws, size_t ws_size,
                              hipStream_t stream)
{
    const float* x      = (const float*)d_in[0];
    const float* w_qkv  = (const float*)d_in[1];
    const float* b_qkv  = (const float*)d_in[2];
    const float* w_attn = (const float*)d_in[3];
    const float* b_attn = (const float*)d_in[4];
    float* out = (float*)d_out;

    // workspace layout (30.4 MB total; xb aliased by ab after gemm1)
    ushort* qkv_b   = (ushort*)d_ws;                                   // 6291456 sh
    float*  attn_ws = (float*)((char*)d_ws + 12582912);                // 2097152 f
    ushort* xb      = (ushort*)((char*)d_ws + 12582912 + 8388608);     // 4194304 sh
    ushort* ab      = xb;                                              // alias (xb dead after gemm1)
    ushort* wb1     = xb + 4194304;                                    // 393216 sh
    ushort* wb2     = wb1 + 393216;                                    // 131072 sh

    cvt_bf16<<<192, 256, 0, stream>>>(w_qkv, wb1, 49152);
    cvt_bf16<<<64, 256, 0, stream>>>(w_attn, wb2, 16384);
    transpose_cvt<<<dim3(16, 8, BATCH), 256, 0, stream>>>(x, xb, CIN, HW);

    gemm_bt<DQKV, CIN, true, true>
        <<<dim3(8, 6, BATCH), 256, 0, stream>>>(wb1, xb, b_qkv, qkv_b);

    attn_kernel<<<dim3(HW / 16, BATCH), 256, 0, stream>>>(qkv_b, attn_ws);

    transpose_cvt<<<dim3(16, 4, BATCH), 256, 0, stream>>>(attn_ws, ab, 256, HW);

    gemm_bt<512, 256, false, false>
        <<<dim3(8, 4, BATCH), 256, 0, stream>>>(wb2, ab, b_attn, out);
}

// Round 4
// 178.182 us; speedup vs baseline: 3.5808x; 1.0386x over previous
//
#include <hip/hip_runtime.h>
#include <math.h>

#define BATCH 8
#define CIN   512
#define DQKV  768
#define NHEAD 8
#define HW    1024

typedef __attribute__((ext_vector_type(8))) short  short8;
typedef __attribute__((ext_vector_type(4))) float  float4v;

__device__ __forceinline__ ushort f2bf(float f) {
    union { float f; unsigned u; } c; c.f = f;
    unsigned u = c.u + 0x7fffu + ((c.u >> 16) & 1u);   // RNE
    return (ushort)(u >> 16);
}

__device__ __forceinline__ void async_ld16(const ushort* g, ushort* l) {
    auto gp = (const __attribute__((address_space(1))) unsigned int*)g;
    auto lp = (__attribute__((address_space(3))) unsigned int*)l;
    __builtin_amdgcn_global_load_lds(gp, lp, 16, 0, 0);
}

// ---------------------------------------------------------------------------
// Transpose + fp32->bf16: per batch, in [K][N] fp32 -> out [N][K] bf16.
// ---------------------------------------------------------------------------
__global__ __launch_bounds__(256)
void transpose_cvt(const float* __restrict__ in, ushort* __restrict__ out,
                   int K, int N)
{
    __shared__ float Ts[64][65];
    const int b  = blockIdx.z;
    const int k0 = blockIdx.y * 64;
    const int n0 = blockIdx.x * 64;
    const int t  = threadIdx.x;
    const float* ib = in + (size_t)b * K * N;
    ushort*      ob = out + (size_t)b * N * K;

    const int r  = t >> 4;
    const int c4 = (t & 15) * 4;
    #pragma unroll
    for (int p = 0; p < 4; ++p) {
        float4 v = *(const float4*)(ib + (size_t)(k0 + r + 16 * p) * N + n0 + c4);
        Ts[r + 16 * p][c4 + 0] = v.x;
        Ts[r + 16 * p][c4 + 1] = v.y;
        Ts[r + 16 * p][c4 + 2] = v.z;
        Ts[r + 16 * p][c4 + 3] = v.w;
    }
    __syncthreads();

    const int nl = t >> 3;
    const int kc = (t & 7) * 8;
    #pragma unroll
    for (int p = 0; p < 2; ++p) {
        int n = nl + 32 * p;
        uint4 u;
        u.x = (uint)f2bf(Ts[kc + 0][n]) | ((uint)f2bf(Ts[kc + 1][n]) << 16);
        u.y = (uint)f2bf(Ts[kc + 2][n]) | ((uint)f2bf(Ts[kc + 3][n]) << 16);
        u.z = (uint)f2bf(Ts[kc + 4][n]) | ((uint)f2bf(Ts[kc + 5][n]) << 16);
        u.w = (uint)f2bf(Ts[kc + 6][n]) | ((uint)f2bf(Ts[kc + 7][n]) << 16);
        *(uint4*)(ob + (size_t)(n0 + n) * K + k0 + kc) = u;
    }
}

// elementwise fp32 -> bf16 (weights), 8 elems/thread
__global__ void cvt_bf16(const float* __restrict__ in, ushort* __restrict__ out, int n8)
{
    int i = blockIdx.x * blockDim.x + threadIdx.x;
    if (i >= n8) return;
    const float4* p = (const float4*)(in + (size_t)i * 8);
    float4 a = p[0], b = p[1];
    uint4 u;
    u.x = (uint)f2bf(a.x) | ((uint)f2bf(a.y) << 16);
    u.y = (uint)f2bf(a.z) | ((uint)f2bf(a.w) << 16);
    u.z = (uint)f2bf(b.x) | ((uint)f2bf(b.y) << 16);
    u.w = (uint)f2bf(b.z) | ((uint)f2bf(b.w) << 16);
    *(uint4*)(out + (size_t)i * 8) = u;
}

// ---------------------------------------------------------------------------
// qk_transform: qkv_b[b][ch][sp] bf16 (ch 0..511 = Q,K) ->
//   Qt/Kt[b][n][sp][32d] bf16 (spatial-major per head).
// Group g 0..15: channel base g*32 (g<8 -> Q head g, else K head g-8).
// 256-sp tiles via LDS (stride 264 sh; store/read bank-uniform).
// ---------------------------------------------------------------------------
__global__ __launch_bounds__(256)
void qk_transform(const ushort* __restrict__ qkv, ushort* __restrict__ Qt,
                  ushort* __restrict__ Kt)
{
    __shared__ ushort Ts[32 * 264];
    const int b   = blockIdx.z;
    const int g   = blockIdx.y;
    const int sp0 = blockIdx.x * 256;
    const int t   = threadIdx.x;

    const ushort* src = qkv + ((size_t)b * DQKV + g * 32) * HW;
    ushort* dst = (g < 8 ? Qt : Kt) + ((size_t)b * NHEAD + (g & 7)) * (HW * 32);

    #pragma unroll
    for (int p = 0; p < 4; ++p) {
        int d = (t >> 5) + p * 8;
        int c = t & 31;
        uint4 u = *(const uint4*)(src + (size_t)d * HW + sp0 + c * 8);
        *(uint4*)&Ts[d * 264 + c * 8] = u;
    }
    __syncthreads();

    ushort* orow = dst + (size_t)(sp0 + t) * 32;
    #pragma unroll
    for (int c = 0; c < 4; ++c) {
        ushort v[8];
        #pragma unroll
        for (int j = 0; j < 8; ++j) v[j] = Ts[(c * 8 + j) * 264 + t];
        *(uint4*)(orow + c * 8) = *(uint4*)v;
    }
}

// ---------------------------------------------------------------------------
// bf16 MFMA GEMM (m97 structure), unchanged from round 3.
// ---------------------------------------------------------------------------
template<int M, int K, bool QSCALE, bool OUTBF>
__global__ __launch_bounds__(256, 2)
void gemm_bt(const ushort* __restrict__ A, const ushort* __restrict__ Bt,
             const float* __restrict__ bias, void* __restrict__ Oo)
{
    __shared__ __align__(16) ushort As[128 * 64];
    __shared__ __align__(16) ushort Bs[128 * 64];

    const int b    = blockIdx.z;
    const int m0   = blockIdx.y * 128;
    const int n0   = blockIdx.x * 128;
    const int t    = threadIdx.x;
    const int lane = t & 63;
    const int wave = t >> 6;
    const int l16  = lane & 15;
    const int quad = lane >> 4;
    const int wm   = (wave & 1) * 64;
    const int wn   = (wave >> 1) * 64;

    const ushort* Bb = Bt + (size_t)b * HW * K;

    float4v acc[4][4];
    #pragma unroll
    for (int i = 0; i < 4; ++i)
        #pragma unroll
        for (int j = 0; j < 4; ++j)
            acc[i][j] = (float4v){0.f, 0.f, 0.f, 0.f};

    const int srow = t >> 3;
    const int sg   = t & 7;

    for (int k0 = 0; k0 < K; k0 += 64) {
        __syncthreads();
        #pragma unroll
        for (int is = 0; is < 4; ++is) {
            int row = srow + is * 32;
            int gch = sg ^ (row & 7);
            async_ld16(A  + (size_t)(m0 + row) * K + k0 + gch * 8,
                       As + (size_t)t * 8 + is * 2048);
            async_ld16(Bb + (size_t)(n0 + row) * K + k0 + gch * 8,
                       Bs + (size_t)t * 8 + is * 2048);
        }
        __syncthreads();

        #pragma unroll
        for (int ks = 0; ks < 2; ++ks) {
            short8 af[4], bf[4];
            #pragma unroll
            for (int i = 0; i < 4; ++i) {
                int row = wm + i * 16 + l16;
                int ch  = (ks * 4 + quad) ^ (row & 7);
                af[i] = *(const short8*)&As[row * 64 + ch * 8];
            }
            #pragma unroll
            for (int j = 0; j < 4; ++j) {
                int row = wn + j * 16 + l16;
                int ch  = (ks * 4 + quad) ^ (row & 7);
                bf[j] = *(const short8*)&Bs[row * 64 + ch * 8];
            }
            #pragma unroll
            for (int i = 0; i < 4; ++i)
                #pragma unroll
                for (int j = 0; j < 4; ++j)
                    acc[i][j] = __builtin_amdgcn_mfma_f32_16x16x32_bf16(
                        af[i], bf[j], acc[i][j], 0, 0, 0);
        }
    }

    #pragma unroll
    for (int i = 0; i < 4; ++i) {
        #pragma unroll
        for (int rr = 0; rr < 4; ++rr) {
            int m = m0 + wm + i * 16 + quad * 4 + rr;
            float bi = bias[m];
            float sc = QSCALE ? ((m < 256) ? 0.17677669529663687f : 1.0f) : 1.0f;
            #pragma unroll
            for (int j = 0; j < 4; ++j) {
                int n = n0 + wn + j * 16 + l16;
                float val = (acc[i][j][rr] + bi) * sc;
                if (OUTBF)
                    ((ushort*)Oo)[((size_t)b * M + m) * HW + n] = f2bf(val);
                else
                    ((float*)Oo)[((size_t)b * M + m) * HW + n] = val;
            }
        }
    }
}

// ---------------------------------------------------------------------------
// MFMA attention core v3. Inputs pre-transposed Qt/Kt[b][n][sp][32d] + V
// natural from qkv_b. All staging = uint4 copies (bank-uniform stores into
// stride-40 rows). Head-axis softmax via fp32 LDS. Epilogue writes bf16
// directly in gemm2's Bt layout ab[b][hw][c].
// ---------------------------------------------------------------------------
__global__ __launch_bounds__(256, 2)
void attn_kernel(const ushort* __restrict__ qkv, const ushort* __restrict__ Qt,
                 const ushort* __restrict__ Kt, ushort* __restrict__ ab)
{
    __shared__ __align__(16) ushort Qs[NHEAD * 16 * 40];
    __shared__ __align__(16) ushort Ks[NHEAD * 32 * 40];
    __shared__ __align__(16) ushort Vs[NHEAD * 32 * 40];
    __shared__ __align__(16) ushort Ws[NHEAD * 16 * 40];
    __shared__ float  Ss[NHEAD * 529];          // [n][q*33 + k]

    const int t    = threadIdx.x;
    const int b    = blockIdx.y;
    const int q0   = blockIdx.x * 16;
    const int wave = t >> 6;
    const int lane = t & 63;
    const int l16  = lane & 15;
    const int quad = lane >> 4;

    const ushort* qk  = qkv + (size_t)b * DQKV * HW;
    const ushort* Qtb = Qt + (size_t)b * NHEAD * HW * 32;
    const ushort* Ktb = Kt + (size_t)b * NHEAD * HW * 32;

    // ---- stage Q tile: Qt[n][q0+q][32d] -> Qs[n][q][d] (uint4 copies) ----
    #pragma unroll
    for (int p = 0; p < 2; ++p) {
        int idx = t + p * 256;            // 0..511
        int n = idx >> 6, q = (idx >> 2) & 15, c = idx & 3;
        uint4 u = *(const uint4*)(Qtb + (size_t)n * (HW * 32) + (size_t)(q0 + q) * 32 + c * 8);
        *(uint4*)&Qs[(n * 16 + q) * 40 + c * 8] = u;
    }

    float4v acc[2][2];
    #pragma unroll
    for (int i = 0; i < 2; ++i)
        #pragma unroll
        for (int j = 0; j < 2; ++j)
            acc[i][j] = (float4v){0.f, 0.f, 0.f, 0.f};

    const int sq = t >> 4;
    const int sk = (t & 15) * 2;

    for (int k0 = 0; k0 < HW; k0 += 32) {
        __syncthreads();

        // ---- stage K (from Kt, direct) and V (natural, direct) ----
        #pragma unroll
        for (int p = 0; p < 4; ++p) {
            int idx = t + p * 256;        // 0..1023
            int n = idx >> 7, r = (idx >> 2) & 31, c = idx & 3;
            uint4 ku = *(const uint4*)(Ktb + (size_t)n * (HW * 32) + (size_t)(k0 + r) * 32 + c * 8);
            *(uint4*)&Ks[(n * 32 + r) * 40 + c * 8] = ku;
            uint4 vu = *(const uint4*)(qk + (size_t)(512 + n * 32 + r) * HW + k0 + c * 8);
            *(uint4*)&Vs[(n * 32 + r) * 40 + c * 8] = vu;
        }
        __syncthreads();

        // ---- logits: one MFMA per 16x16 ----
        #pragma unroll
        for (int hh = 0; hh < 2; ++hh) {
            int h = wave * 2 + hh;
            short8 a = *(const short8*)&Qs[(h * 16 + l16) * 40 + quad * 8];
            #pragma unroll
            for (int ko = 0; ko < 2; ++ko) {
                short8 bfr = *(const short8*)&Ks[(h * 32 + ko * 16 + l16) * 40 + quad * 8];
                float4v s = __builtin_amdgcn_mfma_f32_16x16x32_bf16(
                    a, bfr, (float4v){0.f, 0.f, 0.f, 0.f}, 0, 0, 0);
                float* sp = &Ss[h * 529 + (quad * 4) * 33 + ko * 16 + l16];
                #pragma unroll
                for (int r = 0; r < 4; ++r) sp[r * 33] = s[r];
            }
        }
        __syncthreads();

        // ---- head-axis softmax -> bf16 weights ----
        {
            float v[NHEAD][2];
            float m0v = -1e30f, m1v = -1e30f;
            #pragma unroll
            for (int n = 0; n < NHEAD; ++n) {
                v[n][0] = Ss[n * 529 + sq * 33 + sk + 0];
                v[n][1] = Ss[n * 529 + sq * 33 + sk + 1];
                m0v = fmaxf(m0v, v[n][0]);
                m1v = fmaxf(m1v, v[n][1]);
            }
            float s0 = 0.f, s1 = 0.f;
            #pragma unroll
            for (int n = 0; n < NHEAD; ++n) {
                v[n][0] = __expf(v[n][0] - m0v);
                v[n][1] = __expf(v[n][1] - m1v);
                s0 += v[n][0];
                s1 += v[n][1];
            }
            float i0 = 1.0f / s0, i1 = 1.0f / s1;
            #pragma unroll
            for (int n = 0; n < NHEAD; ++n) {
                uint pk = (uint)f2bf(v[n][0] * i0) | ((uint)f2bf(v[n][1] * i1) << 16);
                *(uint*)&Ws[(n * 16 + sq) * 40 + sk] = pk;
            }
        }
        __syncthreads();

        // ---- PV ----
        #pragma unroll
        for (int hh = 0; hh < 2; ++hh) {
            int h = wave * 2 + hh;
            short8 a = *(const short8*)&Ws[(h * 16 + l16) * 40 + quad * 8];
            #pragma unroll
            for (int dd = 0; dd < 2; ++dd) {
                short8 bfr = *(const short8*)&Vs[(h * 32 + dd * 16 + l16) * 40 + quad * 8];
                acc[hh][dd] = __builtin_amdgcn_mfma_f32_16x16x32_bf16(
                    a, bfr, acc[hh][dd], 0, 0, 0);
            }
        }
    }

    // ---- epilogue: bf16 in gemm2's Bt layout ab[b][hw][c] ----
    // hw = (qg&31)*32 + d,  c = h*32 + (qg>>5)
    #pragma unroll
    for (int hh = 0; hh < 2; ++hh) {
        int h = wave * 2 + hh;
        #pragma unroll
        for (int dd = 0; dd < 2; ++dd) {
            int d = dd * 16 + l16;
            #pragma unroll
            for (int r = 0; r < 4; ++r) {
                int qg = q0 + quad * 4 + r;
                size_t addr = ((size_t)b * HW + (size_t)((qg & 31) * 32 + d)) * 256
                            + h * 32 + (qg >> 5);
                ab[addr] = f2bf(acc[hh][dd][r]);
            }
        }
    }
}

// ---------------------------------------------------------------------------
extern "C" void kernel_launch(void* const* d_in, const int* in_sizes, int n_in,
                              void* d_out, int out_size, void* d_ws, size_t ws_size,
                              hipStream_t stream)
{
    const float* x      = (const float*)d_in[0];
    const float* w_qkv  = (const float*)d_in[1];
    const float* b_qkv  = (const float*)d_in[2];
    const float* w_attn = (const float*)d_in[3];
    const float* b_attn = (const float*)d_in[4];
    float* out = (float*)d_out;

    // workspace (26.2 MB): qkv_b | xb (aliased by Qt+Kt after gemm1) | ab | wb1 | wb2
    ushort* qkv_b = (ushort*)d_ws;                 // 6291456 sh
    ushort* xb    = qkv_b + 6291456;               // 4194304 sh
    ushort* Qt    = xb;                            // alias: 2097152 sh
    ushort* Kt    = xb + 2097152;                  // alias: 2097152 sh
    ushort* ab    = xb + 4194304;                  // 2097152 sh
    ushort* wb1   = ab + 2097152;                  // 393216 sh
    ushort* wb2   = wb1 + 393216;                  // 131072 sh

    cvt_bf16<<<192, 256, 0, stream>>>(w_qkv, wb1, 49152);
    cvt_bf16<<<64, 256, 0, stream>>>(w_attn, wb2, 16384);
    transpose_cvt<<<dim3(16, 8, BATCH), 256, 0, stream>>>(x, xb, CIN, HW);

    gemm_bt<DQKV, CIN, true, true>
        <<<dim3(8, 6, BATCH), 256, 0, stream>>>(wb1, xb, b_qkv, qkv_b);

    qk_transform<<<dim3(4, 16, BATCH), 256, 0, stream>>>(qkv_b, Qt, Kt);

    attn_kernel<<<dim3(HW / 16, BATCH), 256, 0, stream>>>(qkv_b, Qt, Kt, ab);

    gemm_bt<512, 256, false, false>
        <<<dim3(8, 4, BATCH), 256, 0, stream>>>(wb2, ab, b_attn, out);
}

// Round 5
// 162.911 us; speedup vs baseline: 3.9164x; 1.0937x over previous
//
#include <hip/hip_runtime.h>
#include <math.h>

#define BATCH 8
#define CIN   512
#define DQKV  768
#define NHEAD 8
#define HW    1024

typedef __attribute__((ext_vector_type(8))) short  short8;
typedef __attribute__((ext_vector_type(4))) float  float4v;

__device__ __forceinline__ ushort f2bf(float f) {
    union { float f; unsigned u; } c; c.f = f;
    unsigned u = c.u + 0x7fffu + ((c.u >> 16) & 1u);   // RNE
    return (ushort)(u >> 16);
}

__device__ __forceinline__ void async_ld16(const ushort* g, ushort* l) {
    auto gp = (const __attribute__((address_space(1))) unsigned int*)g;
    auto lp = (__attribute__((address_space(3))) unsigned int*)l;
    __builtin_amdgcn_global_load_lds(gp, lp, 16, 0, 0);
}

// ---------------------------------------------------------------------------
// Transpose + fp32->bf16: per batch, in [K][N] fp32 -> out [N][K] bf16.
// ---------------------------------------------------------------------------
__global__ __launch_bounds__(256)
void transpose_cvt(const float* __restrict__ in, ushort* __restrict__ out,
                   int K, int N)
{
    __shared__ float Ts[64][65];
    const int b  = blockIdx.z;
    const int k0 = blockIdx.y * 64;
    const int n0 = blockIdx.x * 64;
    const int t  = threadIdx.x;
    const float* ib = in + (size_t)b * K * N;
    ushort*      ob = out + (size_t)b * N * K;

    const int r  = t >> 4;
    const int c4 = (t & 15) * 4;
    #pragma unroll
    for (int p = 0; p < 4; ++p) {
        float4 v = *(const float4*)(ib + (size_t)(k0 + r + 16 * p) * N + n0 + c4);
        Ts[r + 16 * p][c4 + 0] = v.x;
        Ts[r + 16 * p][c4 + 1] = v.y;
        Ts[r + 16 * p][c4 + 2] = v.z;
        Ts[r + 16 * p][c4 + 3] = v.w;
    }
    __syncthreads();

    const int nl = t >> 3;
    const int kc = (t & 7) * 8;
    #pragma unroll
    for (int p = 0; p < 2; ++p) {
        int n = nl + 32 * p;
        uint4 u;
        u.x = (uint)f2bf(Ts[kc + 0][n]) | ((uint)f2bf(Ts[kc + 1][n]) << 16);
        u.y = (uint)f2bf(Ts[kc + 2][n]) | ((uint)f2bf(Ts[kc + 3][n]) << 16);
        u.z = (uint)f2bf(Ts[kc + 4][n]) | ((uint)f2bf(Ts[kc + 5][n]) << 16);
        u.w = (uint)f2bf(Ts[kc + 6][n]) | ((uint)f2bf(Ts[kc + 7][n]) << 16);
        *(uint4*)(ob + (size_t)(n0 + n) * K + k0 + kc) = u;
    }
}

// elementwise fp32 -> bf16 (weights), 8 elems/thread
__global__ void cvt_bf16(const float* __restrict__ in, ushort* __restrict__ out, int n8)
{
    int i = blockIdx.x * blockDim.x + threadIdx.x;
    if (i >= n8) return;
    const float4* p = (const float4*)(in + (size_t)i * 8);
    float4 a = p[0], b = p[1];
    uint4 u;
    u.x = (uint)f2bf(a.x) | ((uint)f2bf(a.y) << 16);
    u.y = (uint)f2bf(a.z) | ((uint)f2bf(a.w) << 16);
    u.z = (uint)f2bf(b.x) | ((uint)f2bf(b.y) << 16);
    u.w = (uint)f2bf(b.z) | ((uint)f2bf(b.w) << 16);
    *(uint4*)(out + (size_t)i * 8) = u;
}

// ---------------------------------------------------------------------------
// qk_transform: qkv_b[b][ch][sp] bf16 (ch 0..511 = Q,K) ->
//   Qt/Kt[b][n][sp][32d] bf16 (spatial-major per head). Unchanged.
// ---------------------------------------------------------------------------
__global__ __launch_bounds__(256)
void qk_transform(const ushort* __restrict__ qkv, ushort* __restrict__ Qt,
                  ushort* __restrict__ Kt)
{
    __shared__ ushort Ts[32 * 264];
    const int b   = blockIdx.z;
    const int g   = blockIdx.y;
    const int sp0 = blockIdx.x * 256;
    const int t   = threadIdx.x;

    const ushort* src = qkv + ((size_t)b * DQKV + g * 32) * HW;
    ushort* dst = (g < 8 ? Qt : Kt) + ((size_t)b * NHEAD + (g & 7)) * (HW * 32);

    #pragma unroll
    for (int p = 0; p < 4; ++p) {
        int d = (t >> 5) + p * 8;
        int c = t & 31;
        uint4 u = *(const uint4*)(src + (size_t)d * HW + sp0 + c * 8);
        *(uint4*)&Ts[d * 264 + c * 8] = u;
    }
    __syncthreads();

    ushort* orow = dst + (size_t)(sp0 + t) * 32;
    #pragma unroll
    for (int c = 0; c < 4; ++c) {
        ushort v[8];
        #pragma unroll
        for (int j = 0; j < 8; ++j) v[j] = Ts[(c * 8 + j) * 264 + t];
        *(uint4*)(orow + c * 8) = *(uint4*)v;
    }
}

// ---------------------------------------------------------------------------
// bf16 MFMA GEMM (m97 structure), unchanged.
// ---------------------------------------------------------------------------
template<int M, int K, bool QSCALE, bool OUTBF>
__global__ __launch_bounds__(256, 2)
void gemm_bt(const ushort* __restrict__ A, const ushort* __restrict__ Bt,
             const float* __restrict__ bias, void* __restrict__ Oo)
{
    __shared__ __align__(16) ushort As[128 * 64];
    __shared__ __align__(16) ushort Bs[128 * 64];

    const int b    = blockIdx.z;
    const int m0   = blockIdx.y * 128;
    const int n0   = blockIdx.x * 128;
    const int t    = threadIdx.x;
    const int lane = t & 63;
    const int wave = t >> 6;
    const int l16  = lane & 15;
    const int quad = lane >> 4;
    const int wm   = (wave & 1) * 64;
    const int wn   = (wave >> 1) * 64;

    const ushort* Bb = Bt + (size_t)b * HW * K;

    float4v acc[4][4];
    #pragma unroll
    for (int i = 0; i < 4; ++i)
        #pragma unroll
        for (int j = 0; j < 4; ++j)
            acc[i][j] = (float4v){0.f, 0.f, 0.f, 0.f};

    const int srow = t >> 3;
    const int sg   = t & 7;

    for (int k0 = 0; k0 < K; k0 += 64) {
        __syncthreads();
        #pragma unroll
        for (int is = 0; is < 4; ++is) {
            int row = srow + is * 32;
            int gch = sg ^ (row & 7);
            async_ld16(A  + (size_t)(m0 + row) * K + k0 + gch * 8,
                       As + (size_t)t * 8 + is * 2048);
            async_ld16(Bb + (size_t)(n0 + row) * K + k0 + gch * 8,
                       Bs + (size_t)t * 8 + is * 2048);
        }
        __syncthreads();

        #pragma unroll
        for (int ks = 0; ks < 2; ++ks) {
            short8 af[4], bf[4];
            #pragma unroll
            for (int i = 0; i < 4; ++i) {
                int row = wm + i * 16 + l16;
                int ch  = (ks * 4 + quad) ^ (row & 7);
                af[i] = *(const short8*)&As[row * 64 + ch * 8];
            }
            #pragma unroll
            for (int j = 0; j < 4; ++j) {
                int row = wn + j * 16 + l16;
                int ch  = (ks * 4 + quad) ^ (row & 7);
                bf[j] = *(const short8*)&Bs[row * 64 + ch * 8];
            }
            #pragma unroll
            for (int i = 0; i < 4; ++i)
                #pragma unroll
                for (int j = 0; j < 4; ++j)
                    acc[i][j] = __builtin_amdgcn_mfma_f32_16x16x32_bf16(
                        af[i], bf[j], acc[i][j], 0, 0, 0);
        }
    }

    #pragma unroll
    for (int i = 0; i < 4; ++i) {
        #pragma unroll
        for (int rr = 0; rr < 4; ++rr) {
            int m = m0 + wm + i * 16 + quad * 4 + rr;
            float bi = bias[m];
            float sc = QSCALE ? ((m < 256) ? 0.17677669529663687f : 1.0f) : 1.0f;
            #pragma unroll
            for (int j = 0; j < 4; ++j) {
                int n = n0 + wn + j * 16 + l16;
                float val = (acc[i][j][rr] + bi) * sc;
                if (OUTBF)
                    ((ushort*)Oo)[((size_t)b * M + m) * HW + n] = f2bf(val);
                else
                    ((float*)Oo)[((size_t)b * M + m) * HW + n] = val;
            }
        }
    }
}

// ---------------------------------------------------------------------------
// MFMA attention core v4 — register softmax.
// Block = (b, 32q), 512 threads (8 waves), k-tile 128, 8 iters, 2 barriers/it.
// Logits: S^T = mfma(K_frag, Q_frag) per head -> all 8 heads live in each
// wave's registers (wave owns a 16-k chunk); head-axis softmax is pure
// register math. Weights go to LDS (the only buffer) as packed b64 writes
// (4 k-contiguous values/lane — conflict-free) for the C->A layout change.
// PV: wave = 1 head; W A-frags from LDS (stride-68-dword rows: uniform
// 8/bank), V B-frags direct from global qkv (natural [d][k] = B layout).
// Q/K fragments load direct from Qt/Kt (L2-resident), no staging LDS.
// ---------------------------------------------------------------------------
#define WROW 136   // Ws row stride in shorts (128 data + 8 pad)

__global__ __launch_bounds__(512, 2)
void attn_kernel(const ushort* __restrict__ qkv, const ushort* __restrict__ Qt,
                 const ushort* __restrict__ Kt, ushort* __restrict__ ab)
{
    __shared__ __align__(16) ushort Ws[NHEAD * 32 * WROW];   // 69632 B

    const int t    = threadIdx.x;
    const int b    = blockIdx.y;
    const int q0   = blockIdx.x * 32;
    const int wave = t >> 6;          // logits: k-chunk; PV: head
    const int lane = t & 63;
    const int l16  = lane & 15;
    const int quad = lane >> 4;

    const ushort* Vb  = qkv + ((size_t)b * DQKV + 512) * HW;
    const ushort* Qtb = Qt + (size_t)b * (NHEAD * HW * 32);
    const ushort* Ktb = Kt + (size_t)b * (NHEAD * HW * 32);

    // ---- preload Q B-frags (loop-invariant): lane l16 = q, quad*8 = d ----
    short8 qf[NHEAD][2];
    #pragma unroll
    for (int h = 0; h < NHEAD; ++h)
        #pragma unroll
        for (int qs = 0; qs < 2; ++qs)
            qf[h][qs] = *(const short8*)(Qtb + ((size_t)h * HW + q0 + qs * 16 + l16) * 32 + quad * 8);

    float4v oacc[2][2];               // [qsub][dsub], head = wave
    #pragma unroll
    for (int i = 0; i < 2; ++i)
        #pragma unroll
        for (int j = 0; j < 2; ++j)
            oacc[i][j] = (float4v){0.f, 0.f, 0.f, 0.f};

    for (int k0 = 0; k0 < HW; k0 += 128) {
        // ---- logits: S^T[k][q] for all 8 heads, wave's 16-k chunk ----
        const int kk = k0 + wave * 16 + l16;      // A-frag k row for this lane
        float4v S[2][NHEAD];
        #pragma unroll
        for (int h = 0; h < NHEAD; ++h) {
            short8 kf = *(const short8*)(Ktb + ((size_t)h * HW + kk) * 32 + quad * 8);
            S[0][h] = __builtin_amdgcn_mfma_f32_16x16x32_bf16(
                kf, qf[h][0], (float4v){0.f, 0.f, 0.f, 0.f}, 0, 0, 0);
            S[1][h] = __builtin_amdgcn_mfma_f32_16x16x32_bf16(
                kf, qf[h][1], (float4v){0.f, 0.f, 0.f, 0.f}, 0, 0, 0);
        }

        // ---- head-axis softmax in registers; pack b64 per head ----
        uint2 wpk[2][NHEAD];
        #pragma unroll
        for (int qs = 0; qs < 2; ++qs) {
            float4v mx = S[qs][0];
            #pragma unroll
            for (int h = 1; h < NHEAD; ++h)
                #pragma unroll
                for (int r = 0; r < 4; ++r) mx[r] = fmaxf(mx[r], S[qs][h][r]);
            float e[NHEAD][4];
            float4v sum = (float4v){0.f, 0.f, 0.f, 0.f};
            #pragma unroll
            for (int h = 0; h < NHEAD; ++h)
                #pragma unroll
                for (int r = 0; r < 4; ++r) {
                    e[h][r] = __expf(S[qs][h][r] - mx[r]);
                    sum[r] += e[h][r];
                }
            float4v inv;
            #pragma unroll
            for (int r = 0; r < 4; ++r) inv[r] = __builtin_amdgcn_rcpf(sum[r]);
            #pragma unroll
            for (int h = 0; h < NHEAD; ++h) {
                uint2 pk;
                pk.x = (uint)f2bf(e[h][0] * inv[0]) | ((uint)f2bf(e[h][1] * inv[1]) << 16);
                pk.y = (uint)f2bf(e[h][2] * inv[2]) | ((uint)f2bf(e[h][3] * inv[3]) << 16);
                wpk[qs][h] = pk;
            }
        }

        __syncthreads();   // prev iter's PV done reading Ws

        // ---- W writes: W[q = qs*16+l16][k = wave*16 + quad*4 + 0..3] ----
        #pragma unroll
        for (int qs = 0; qs < 2; ++qs)
            #pragma unroll
            for (int h = 0; h < NHEAD; ++h)
                *(uint2*)&Ws[(size_t)(h * 32 + qs * 16 + l16) * WROW + wave * 16 + quad * 4]
                    = wpk[qs][h];

        __syncthreads();   // Ws ready

        // ---- PV: head = wave; O[q][d] += W[q][k] V[d][k] ----
        #pragma unroll
        for (int ks = 0; ks < 4; ++ks) {
            short8 wf[2], vf[2];
            #pragma unroll
            for (int qs = 0; qs < 2; ++qs)
                wf[qs] = *(const short8*)&Ws[(size_t)(wave * 32 + qs * 16 + l16) * WROW + ks * 32 + quad * 8];
            #pragma unroll
            for (int ds = 0; ds < 2; ++ds)
                vf[ds] = *(const short8*)(Vb + (size_t)(wave * 32 + ds * 16 + l16) * HW + k0 + ks * 32 + quad * 8);
            #pragma unroll
            for (int qs = 0; qs < 2; ++qs)
                #pragma unroll
                for (int ds = 0; ds < 2; ++ds)
                    oacc[qs][ds] = __builtin_amdgcn_mfma_f32_16x16x32_bf16(
                        wf[qs], vf[ds], oacc[qs][ds], 0, 0, 0);
        }
    }

    // ---- epilogue: bf16 in gemm2's Bt layout ab[b][hw][c] ----
    // qg = q0 + qs*16 + quad*4 + r,  d = ds*16 + l16,  c = wave*32 + (qg>>5)
    #pragma unroll
    for (int qs = 0; qs < 2; ++qs)
        #pragma unroll
        for (int ds = 0; ds < 2; ++ds) {
            int d = ds * 16 + l16;
            #pragma unroll
            for (int r = 0; r < 4; ++r) {
                int qg = q0 + qs * 16 + quad * 4 + r;
                size_t addr = ((size_t)b * HW + (size_t)((qg & 31) * 32 + d)) * 256
                            + wave * 32 + (qg >> 5);
                ab[addr] = f2bf(oacc[qs][ds][r]);
            }
        }
}

// ---------------------------------------------------------------------------
extern "C" void kernel_launch(void* const* d_in, const int* in_sizes, int n_in,
                              void* d_out, int out_size, void* d_ws, size_t ws_size,
                              hipStream_t stream)
{
    const float* x      = (const float*)d_in[0];
    const float* w_qkv  = (const float*)d_in[1];
    const float* b_qkv  = (const float*)d_in[2];
    const float* w_attn = (const float*)d_in[3];
    const float* b_attn = (const float*)d_in[4];
    float* out = (float*)d_out;

    // workspace (26.2 MB): qkv_b | xb (aliased by Qt+Kt after gemm1) | ab | wb1 | wb2
    ushort* qkv_b = (ushort*)d_ws;                 // 6291456 sh
    ushort* xb    = qkv_b + 6291456;               // 4194304 sh
    ushort* Qt    = xb;                            // alias: 2097152 sh
    ushort* Kt    = xb + 2097152;                  // alias: 2097152 sh
    ushort* ab    = xb + 4194304;                  // 2097152 sh
    ushort* wb1   = ab + 2097152;                  // 393216 sh
    ushort* wb2   = wb1 + 393216;                  // 131072 sh

    cvt_bf16<<<192, 256, 0, stream>>>(w_qkv, wb1, 49152);
    cvt_bf16<<<64, 256, 0, stream>>>(w_attn, wb2, 16384);
    transpose_cvt<<<dim3(16, 8, BATCH), 256, 0, stream>>>(x, xb, CIN, HW);

    gemm_bt<DQKV, CIN, true, true>
        <<<dim3(8, 6, BATCH), 256, 0, stream>>>(wb1, xb, b_qkv, qkv_b);

    qk_transform<<<dim3(4, 16, BATCH), 256, 0, stream>>>(qkv_b, Qt, Kt);

    attn_kernel<<<dim3(HW / 32, BATCH), 512, 0, stream>>>(qkv_b, Qt, Kt, ab);

    gemm_bt<512, 256, false, false>
        <<<dim3(8, 4, BATCH), 256, 0, stream>>>(wb2, ab, b_attn, out);
}